// Round 4
// baseline (128.747 us; speedup 1.0000x reference)
//
#include <hip/hip_runtime.h>
#include <stdint.h>

typedef unsigned long long u64;
typedef unsigned int u32;

#define BB 32
#define NN 30000
#define NC 81
#define MAX_DET 100
#define MIN_CONF 0.7f
#define IOU_THR 0.3f
#define BCAP 192               // per-(image,class) cap; mean 111, sd 10.5 (7.7 sigma); validated r1-r3
#define SCAP 10240             // per-image survivor cap; ~8900 expected
#define NB 640                 // score buckets for [0.7,1.0): 615 used
#define BASE13 (0x3F333333u >> 13)
#define NPAIR (BB * (NC - 1))  // 2560
#define WPB 4                  // (image,class) pairs (waves) per classnms block

// ws layout (PRE path):
//   0         : bucketCount u32[BB*NC]
//   12288     : survCount   u32[BB]
//   16384     : bucketKeys  u64[BB*NC*BCAP]      (3,981,312 B)
//   3,997,696 : bucketBox   float4[BB*NC*BCAP]   (7,962,624 B)
//   11,960,320: survKeys    u64[BB*SCAP]         (2,621,440 B)   total 14,581,760 B
// fallback (!PRE, ws too small): survKeys at 3,997,696 (r3 layout, on-demand decode)

// ---------- decode (bit-exact vs reference; validated absmax 0 in r1-r3) ----------
__device__ __forceinline__ void decode_box(const float* __restrict__ rois,
                                           const float* __restrict__ cls,
                                           long long bn,
                                           float wy1, float wx1, float wy2, float wx2,
                                           float& y1, float& x1, float& y2, float& x2) {
#pragma clang fp contract(off)
    const float4 r   = *reinterpret_cast<const float4*>(rois + bn * 4);
    const float2 d01 = *reinterpret_cast<const float2*>(cls + bn * 6);
    const float2 d23 = *reinterpret_cast<const float2*>(cls + bn * 6 + 2);
    float dy = d01.x * 0.1f, dx = d01.y * 0.1f;
    float dh = d23.x * 0.2f, dw = d23.y * 0.2f;
    float h = r.z - r.x, w = r.w - r.y;
    float cy = r.x + 0.5f * h + dy * h;
    float cx = r.y + 0.5f * w + dx * w;
    h = h * expf(dh);
    w = w * expf(dw);
    y1 = cy - 0.5f * h; x1 = cx - 0.5f * w;
    y2 = cy + 0.5f * h; x2 = cx + 0.5f * w;
    y1 = fminf(fmaxf(y1, wy1), wy2);
    y2 = fminf(fmaxf(y2, wy1), wy2);
    x1 = fminf(fmaxf(x1, wx1), wx2);
    x2 = fminf(fmaxf(x2, wx1), wx2);
}

// ---------- kernel 1: filter + decode (streaming, coalesced) + scatter to buckets ----------
template <bool PRE>
__global__ void filter_kernel(const float* __restrict__ rois,
                              const float* __restrict__ cls,
                              const float* __restrict__ window,
                              u64* __restrict__ bucketKeys,
                              float4* __restrict__ bucketBox,
                              u32* __restrict__ bucketCount) {
    const int blocksPerImg = (NN + 255) / 256;
    const int b = blockIdx.x / blocksPerImg;
    const int n = (blockIdx.x % blocksPerImg) * 256 + threadIdx.x;
    if (n >= NN) return;
    const long long bn = (long long)b * NN + n;
    const float2 cs = *reinterpret_cast<const float2*>(cls + bn * 6 + 4);
    const int cid = (int)cs.x;
    const float score = cs.y;
    if (cid > 0 && score >= MIN_CONF) {
        u32 slot = atomicAdd(&bucketCount[b * NC + cid], 1u);
        if (slot < BCAP) {
            const long long dst = ((long long)(b * NC + cid)) * BCAP + slot;
            // final-format key: score (desc) | (0x7FFF-n) (asc idx) | cid
            bucketKeys[dst] = ((u64)__float_as_uint(score) << 32)
                            | ((u64)(0x7FFF - n) << 7) | (u64)cid;
            if (PRE) {
                float y1, x1, y2, x2;
                decode_box(rois, cls, bn,
                           window[b * 4 + 0], window[b * 4 + 1],
                           window[b * 4 + 2], window[b * 4 + 3],
                           y1, x1, y2, x2);
                bucketBox[dst] = make_float4(y1, x1, y2, x2);
            }
        }
    }
}

// ---------- kernel 2: one wave per (image,class); load-order masks + ballot fixpoint ----------
template <bool PRE>
__global__ __launch_bounds__(WPB * 64) void classnms_kernel(
        const float* __restrict__ rois,
        const float* __restrict__ cls,
        const float* __restrict__ window,
        const u64* __restrict__ bucketKeys,
        const float4* __restrict__ bucketBox,
        const u32* __restrict__ bucketCount,
        u64* __restrict__ survKeys,
        u32* __restrict__ survCount) {
#pragma clang fp contract(off)
    const int wave = threadIdx.x >> 6;
    const int lane = threadIdx.x & 63;
    const int pair = blockIdx.x * WPB + wave;
    const int b = pair / (NC - 1);
    const int cid = 1 + pair % (NC - 1);
    const u32 cnt = min(bucketCount[b * NC + cid], (u32)BCAP);
    if (cnt == 0) return;               // per-wave exit; no barriers anywhere

    __shared__ u64 sKey[WPB][BCAP];     // wave-private regions
    __shared__ float4 sBox[WPB][BCAP];
    u64* wKey = sKey[wave];
    float4* wBox = sBox[wave];

    const long long base = ((long long)(b * NC + cid)) * BCAP;

    // --- coalesced load of keys + boxes; lane owns load indices lane, lane+64, lane+128 ---
    u64 myKey[3]; float4 myBox[3]; float myAr[3]; bool own[3];
#pragma unroll
    for (int s = 0; s < 3; ++s) {
        const u32 idx = (u32)lane + 64u * (u32)s;
        own[s] = idx < cnt;
        myKey[s] = 0ull;
        myBox[s] = make_float4(0.f, 0.f, 0.f, 0.f);
        if (own[s]) {
            u64 k = bucketKeys[base + idx];
            myKey[s] = k;
            if (PRE) {
                myBox[s] = bucketBox[base + idx];
            } else {
                int n = 0x7FFF - (int)((k >> 7) & 0x7FFF);
                float y1, x1, y2, x2;
                decode_box(rois, cls, (long long)b * NN + n,
                           window[b * 4 + 0], window[b * 4 + 1],
                           window[b * 4 + 2], window[b * 4 + 3],
                           y1, x1, y2, x2);
                myBox[s] = make_float4(y1, x1, y2, x2);
            }
            wKey[idx] = myKey[s];
            wBox[idx] = myBox[s];
        }
        myAr[s] = (myBox[s].z - myBox[s].x) * (myBox[s].w - myBox[s].y);
    }

    // --- suppressor masks in LOAD order: bit j of mskW[s] <=> cand j suppresses my slot s ---
    u64 msk0[3] = {0,0,0}, msk1[3] = {0,0,0}, msk2[3] = {0,0,0};

#define IOU_BODY(S, MSK)                                                           \
    if (own[S] && kj > myKey[S]) {  /* j earlier in greedy order than me */        \
        float yy1 = fmaxf(bj.x, myBox[S].x), xx1 = fmaxf(bj.y, myBox[S].y);        \
        float yy2 = fminf(bj.z, myBox[S].z), xx2 = fminf(bj.w, myBox[S].w);        \
        float inter = fmaxf(yy2 - yy1, 0.f) * fmaxf(xx2 - xx1, 0.f);               \
        float iou = inter / (aj + myAr[S] - inter + 1e-8f);                        \
        if (iou > IOU_THR) MSK[S] |= bit;                                          \
    }

    u32 j = 0;
    const u32 e0 = min(cnt, 64u), e1 = min(cnt, 128u);
#pragma unroll 2
    for (; j < e0; ++j) {
        u64 kj = wKey[j]; float4 bj = wBox[j];
        float aj = (bj.z - bj.x) * (bj.w - bj.y);
        u64 bit = 1ull << (j & 63);
        IOU_BODY(0, msk0) IOU_BODY(1, msk0) IOU_BODY(2, msk0)
    }
#pragma unroll 2
    for (; j < e1; ++j) {
        u64 kj = wKey[j]; float4 bj = wBox[j];
        float aj = (bj.z - bj.x) * (bj.w - bj.y);
        u64 bit = 1ull << (j & 63);
        IOU_BODY(0, msk1) IOU_BODY(1, msk1) IOU_BODY(2, msk1)
    }
#pragma unroll 2
    for (; j < cnt; ++j) {
        u64 kj = wKey[j]; float4 bj = wBox[j];
        float aj = (bj.z - bj.x) * (bj.w - bj.y);
        u64 bit = 1ull << (j & 63);
        IOU_BODY(0, msk2) IOU_BODY(1, msk2) IOU_BODY(2, msk2)
    }
#undef IOU_BODY

    // --- ballot fixpoint: dead iff any alive suppressor; alive iff all suppressors dead ---
    u64 KNOWN[3], ALIVE[3] = {0ull, 0ull, 0ull};
#pragma unroll
    for (int w = 0; w < 3; ++w) {
        int rem = (int)cnt - 64 * w;
        KNOWN[w] = (rem <= 0) ? ~0ull : ((rem >= 64) ? 0ull : (~0ull << rem));
    }
    while ((KNOWN[0] & KNOWN[1] & KNOWN[2]) != ~0ull) {
        bool kn[3] = {false, false, false}, al[3] = {false, false, false};
#pragma unroll
        for (int s = 0; s < 3; ++s) {
            if (own[s] && !((KNOWN[s] >> lane) & 1ull)) {
                u64 supAlive = (msk0[s] & ALIVE[0]) | (msk1[s] & ALIVE[1]) | (msk2[s] & ALIVE[2]);
                if (supAlive != 0ull) kn[s] = true;                       // dead
                else {
                    u64 supUnk = (msk0[s] & ~KNOWN[0]) | (msk1[s] & ~KNOWN[1]) | (msk2[s] & ~KNOWN[2]);
                    if (supUnk == 0ull) { kn[s] = true; al[s] = true; }   // alive
                }
            }
        }
#pragma unroll
        for (int s = 0; s < 3; ++s) {
            KNOWN[s] |= __ballot(kn[s]);
            ALIVE[s] |= __ballot(al[s]);
        }
    }

    // --- bulk append survivors, one atomic per wave; keys already final-format ---
    u32 total = (u32)(__popcll(ALIVE[0]) + __popcll(ALIVE[1]) + __popcll(ALIVE[2]));
    if (total == 0) return;
    u32 abase = 0;
    if (lane == 0) abase = atomicAdd(survCount + b, total);
    abase = __shfl(abase, 0);
    const u32 pre0 = (u32)__popcll(ALIVE[0]);
    const u32 pre1 = pre0 + (u32)__popcll(ALIVE[1]);
    const u64 ltm = (1ull << lane) - 1ull;
#pragma unroll
    for (int s = 0; s < 3; ++s) {
        if ((ALIVE[s] >> lane) & 1ull) {
            u32 off = (s == 0 ? 0u : (s == 1 ? pre0 : pre1)) + (u32)__popcll(ALIVE[s] & ltm);
            u32 d = abase + off;
            if (d < SCAP) survKeys[(long long)b * SCAP + d] = myKey[s];
        }
    }
}

// ---------- kernel 3: per-image top-100, all phases parallel (validated r3) ----------
__global__ __launch_bounds__(1024) void select_kernel(const float* __restrict__ rois,
                                                      const float* __restrict__ cls,
                                                      const float* __restrict__ window,
                                                      const u64* __restrict__ survKeys,
                                                      const u32* __restrict__ survCount,
                                                      float* __restrict__ out) {
#pragma clang fp contract(off)
    const int b = blockIdx.x;
    const int tid = threadIdx.x;
    const int lane = tid & 63, wid = tid >> 6;
    const u32 S = min(survCount[b], (u32)SCAP);
    __shared__ u32 hist[NB];
    __shared__ u32 wsum[16];
    __shared__ int sT;
    __shared__ u32 collCnt;
    __shared__ u64 coll[1024];
    __shared__ u64 order[MAX_DET];

    if (tid < NB) hist[tid] = 0u;
    if (tid == 0) { sT = 0; collCnt = 0u; }
    __syncthreads();

    const u64* sk = survKeys + (long long)b * SCAP;
    for (u32 i = tid; i < S; i += 1024) {
        u32 bkt = (u32)(sk[i] >> 45) - BASE13;
        atomicAdd(&hist[bkt], 1u);
    }
    __syncthreads();

    u32 v = (tid < NB) ? hist[tid] : 0u;
    u32 ws = v;
#pragma unroll
    for (int off = 1; off < 64; off <<= 1) ws += __shfl_xor(ws, off);
    if (lane == 0) wsum[wid] = ws;
    __syncthreads();

    bool cond = false;
    if (tid < NB) {
        u32 suffix = 0;
        for (int w = wid + 1; w < 16; ++w) suffix += wsum[w];
        const int end = (wid + 1) * 64;
        for (int i = tid; i < end; ++i) suffix += hist[i];
        cond = suffix >= MAX_DET;
    }
    u64 bal = __ballot(cond);
    if (lane == 0 && bal != 0ull) {
        int hb = 63 - __clzll((long long)bal);
        atomicMax(&sT, wid * 64 + hb);
    }
    __syncthreads();

    const int T = sT;
    for (u32 i = tid; i < S; i += 1024) {
        u64 k = sk[i];
        int bkt = (int)((u32)(k >> 45) - BASE13);
        if (bkt >= T) {
            u32 d = atomicAdd(&collCnt, 1u);
            if (d < 1024u) coll[d] = k;
        }
    }
    if (tid < MAX_DET) order[tid] = 0ull;
    __syncthreads();

    const u32 C = min(collCnt, 1024u);
    for (u32 t = tid; t < C; t += 1024) {
        u64 k = coll[t];
        u32 r = 0;
        for (u32 i = 0; i < C; ++i) r += (u32)(coll[i] > k);
        if (r < MAX_DET) order[r] = k;
    }
    __syncthreads();

    if (tid < MAX_DET) {
        u64 m = order[tid];
        float* row = out + ((long long)b * MAX_DET + tid) * 6;
        if (m != 0ull) {
            int n = 0x7FFF - (int)((m >> 7) & 0x7FFF);
            int cid = (int)(m & 0x7F);
            float score = __uint_as_float((u32)(m >> 32));
            float y1, x1, y2, x2;
            decode_box(rois, cls, (long long)b * NN + n,
                       window[b * 4 + 0], window[b * 4 + 1], window[b * 4 + 2], window[b * 4 + 3],
                       y1, x1, y2, x2);
            row[0] = y1; row[1] = x1; row[2] = y2; row[3] = x2;
            row[4] = (float)cid; row[5] = score;
        } else {
            row[0] = 0.f; row[1] = 0.f; row[2] = 0.f;
            row[3] = 0.f; row[4] = 0.f; row[5] = 0.f;
        }
    }
}

extern "C" void kernel_launch(void* const* d_in, const int* in_sizes, int n_in,
                              void* d_out, int out_size, void* d_ws, size_t ws_size,
                              hipStream_t stream) {
    const float* rois   = (const float*)d_in[0];
    const float* cls    = (const float*)d_in[1];
    const float* window = (const float*)d_in[2];
    float* out = (float*)d_out;

    u32* bucketCount = (u32*)d_ws;
    u32* survCount   = (u32*)((char*)d_ws + 12288);
    u64* bucketKeys  = (u64*)((char*)d_ws + 16384);
    const size_t bkBytes  = (size_t)BB * NC * BCAP * 8;    // 3,981,312
    const size_t boxBytes = (size_t)BB * NC * BCAP * 16;   // 7,962,624
    const size_t preNeed  = 16384 + bkBytes + boxBytes + (size_t)BB * SCAP * 8;

    hipMemsetAsync(d_ws, 0, 16384, stream);
    const int blocksPerImg = (NN + 255) / 256;

    if (ws_size >= preNeed) {
        float4* bucketBox = (float4*)((char*)d_ws + 16384 + bkBytes);
        u64* survKeys     = (u64*)((char*)d_ws + 16384 + bkBytes + boxBytes);
        filter_kernel<true><<<BB * blocksPerImg, 256, 0, stream>>>(
            rois, cls, window, bucketKeys, bucketBox, bucketCount);
        classnms_kernel<true><<<NPAIR / WPB, WPB * 64, 0, stream>>>(
            rois, cls, window, bucketKeys, bucketBox, bucketCount, survKeys, survCount);
        select_kernel<<<BB, 1024, 0, stream>>>(rois, cls, window, survKeys, survCount, out);
    } else {
        // fallback: r3 layout, on-demand decode (deterministic: ws_size fixed per session)
        u64* survKeys = (u64*)((char*)d_ws + 16384 + bkBytes);
        filter_kernel<false><<<BB * blocksPerImg, 256, 0, stream>>>(
            rois, cls, window, bucketKeys, nullptr, bucketCount);
        classnms_kernel<false><<<NPAIR / WPB, WPB * 64, 0, stream>>>(
            rois, cls, window, bucketKeys, nullptr, bucketCount, survKeys, survCount);
        select_kernel<<<BB, 1024, 0, stream>>>(rois, cls, window, survKeys, survCount, out);
    }
}

// Round 5
// 106.554 us; speedup vs baseline: 1.2083x; 1.2083x over previous
//
#include <hip/hip_runtime.h>
#include <stdint.h>

typedef unsigned long long u64;
typedef unsigned int u32;

#define BB 32
#define NN 30000
#define NC 81
#define MAX_DET 100
#define MIN_CONF 0.7f
#define IOU_THR 0.3f
#define BCAP 192               // per-(image,class) cap; mean 111, sd 10.5 (7.7 sigma); validated r1-r4
#define SCAP 10240             // per-image survivor cap; ~8900 expected
#define NB 640                 // score buckets for [0.7,1.0): 615 used
#define BASE13 (0x3F333333u >> 13)
#define NPAIR (BB * (NC - 1))  // 2560

// ws layout (PRE path):
//   0         : bucketCount u32[BB*NC]
//   12288     : survCount   u32[BB]
//   16384     : bucketKeys  u64[BB*NC*BCAP]      (3,981,312 B)
//   3,997,696 : bucketBox   float4[BB*NC*BCAP]   (7,962,624 B)
//   11,960,320: survKeys    u64[BB*SCAP]         (2,621,440 B)   total 14,581,760 B

// ---------- decode (bit-exact vs reference; validated absmax 0 in r1-r4) ----------
__device__ __forceinline__ void decode_box(const float* __restrict__ rois,
                                           const float* __restrict__ cls,
                                           long long bn,
                                           float wy1, float wx1, float wy2, float wx2,
                                           float& y1, float& x1, float& y2, float& x2) {
#pragma clang fp contract(off)
    const float4 r   = *reinterpret_cast<const float4*>(rois + bn * 4);
    const float2 d01 = *reinterpret_cast<const float2*>(cls + bn * 6);
    const float2 d23 = *reinterpret_cast<const float2*>(cls + bn * 6 + 2);
    float dy = d01.x * 0.1f, dx = d01.y * 0.1f;
    float dh = d23.x * 0.2f, dw = d23.y * 0.2f;
    float h = r.z - r.x, w = r.w - r.y;
    float cy = r.x + 0.5f * h + dy * h;
    float cx = r.y + 0.5f * w + dx * w;
    h = h * expf(dh);
    w = w * expf(dw);
    y1 = cy - 0.5f * h; x1 = cx - 0.5f * w;
    y2 = cy + 0.5f * h; x2 = cx + 0.5f * w;
    y1 = fminf(fmaxf(y1, wy1), wy2);
    y2 = fminf(fmaxf(y2, wy1), wy2);
    x1 = fminf(fmaxf(x1, wx1), wx2);
    x2 = fminf(fmaxf(x2, wx1), wx2);
}

// ---------- kernel 1: filter + decode (streaming) + scatter to buckets ----------
template <bool PRE>
__global__ void filter_kernel(const float* __restrict__ rois,
                              const float* __restrict__ cls,
                              const float* __restrict__ window,
                              u64* __restrict__ bucketKeys,
                              float4* __restrict__ bucketBox,
                              u32* __restrict__ bucketCount) {
    const int blocksPerImg = (NN + 255) / 256;
    const int b = blockIdx.x / blocksPerImg;
    const int n = (blockIdx.x % blocksPerImg) * 256 + threadIdx.x;
    if (n >= NN) return;
    const long long bn = (long long)b * NN + n;
    const float2 cs = *reinterpret_cast<const float2*>(cls + bn * 6 + 4);
    const int cid = (int)cs.x;
    const float score = cs.y;
    if (cid > 0 && score >= MIN_CONF) {
        u32 slot = atomicAdd(&bucketCount[b * NC + cid], 1u);
        if (slot < BCAP) {
            const long long dst = ((long long)(b * NC + cid)) * BCAP + slot;
            // final-format key: score (desc) | (0x7FFF-n) (asc idx) | cid
            bucketKeys[dst] = ((u64)__float_as_uint(score) << 32)
                            | ((u64)(0x7FFF - n) << 7) | (u64)cid;
            if (PRE) {
                float y1, x1, y2, x2;
                decode_box(rois, cls, bn,
                           window[b * 4 + 0], window[b * 4 + 1],
                           window[b * 4 + 2], window[b * 4 + 3],
                           y1, x1, y2, x2);
                bucketBox[dst] = make_float4(y1, x1, y2, x2);
            }
        }
    }
}

// ---------- kernel 2: one block (192 thr = 3 waves) per (image,class) ----------
// Phase 1: load/decode candidate per lane -> LDS.  Phase 2: offset-pairing, each
// unordered pair's IoU computed ONCE; suppressor bits merged via LDS atomicOr.
// Phase 3 (wave 0): validated ballot fixpoint + bulk survivor append.
template <bool PRE>
__global__ __launch_bounds__(BCAP) void classnms_kernel(
        const float* __restrict__ rois,
        const float* __restrict__ cls,
        const float* __restrict__ window,
        const u64* __restrict__ bucketKeys,
        const float4* __restrict__ bucketBox,
        const u32* __restrict__ bucketCount,
        u64* __restrict__ survKeys,
        u32* __restrict__ survCount) {
#pragma clang fp contract(off)
    const int pair = blockIdx.x;
    const int b = pair / (NC - 1);
    const int cid = 1 + pair % (NC - 1);
    const u32 cnt = min(bucketCount[b * NC + cid], (u32)BCAP);
    if (cnt == 0) return;               // block-uniform exit (before any barrier)

    const int l = threadIdx.x;          // candidate index == thread index
    const int lane = l & 63;

    __shared__ u64 kKey[BCAP];
    __shared__ float4 kBox[BCAP];
    __shared__ float kArea[BCAP];
    __shared__ u64 mask[BCAP][3];       // suppressor bitmask per candidate (load-index bits)

    const long long base = ((long long)(b * NC + cid)) * BCAP;

    // --- phase 1: one candidate per thread ---
    mask[l][0] = 0ull; mask[l][1] = 0ull; mask[l][2] = 0ull;
    u64 myKey = 0ull; float4 my = make_float4(0.f, 0.f, 0.f, 0.f); float myAr = 0.f;
    const bool act = (u32)l < cnt;
    if (act) {
        myKey = bucketKeys[base + l];
        if (PRE) {
            my = bucketBox[base + l];
        } else {
            int n = 0x7FFF - (int)((myKey >> 7) & 0x7FFF);
            float y1, x1, y2, x2;
            decode_box(rois, cls, (long long)b * NN + n,
                       window[b * 4 + 0], window[b * 4 + 1],
                       window[b * 4 + 2], window[b * 4 + 3],
                       y1, x1, y2, x2);
            my = make_float4(y1, x1, y2, x2);
        }
        myAr = (my.z - my.x) * (my.w - my.y);
        kKey[l] = myKey; kBox[l] = my; kArea[l] = myAr;
    }
    __syncthreads();

    // --- phase 2: each unordered pair once; t = 1..floor(cnt/2) ---
    if (act) {
        u64 m0 = 0ull, m1 = 0ull, m2 = 0ull;            // j suppresses me (register)
        const u32 myW = (u32)l >> 6;
        const u64 myBit = 1ull << (l & 63);
        const u32 T = cnt >> 1;
        for (u32 t = 1; t <= T; ++t) {
            u32 j = (u32)l + t; if (j >= cnt) j -= cnt;
            u64 kj = kKey[j];
            float4 bj = kBox[j];
            float aj = kArea[j];
            float yy1 = fmaxf(bj.x, my.x), xx1 = fmaxf(bj.y, my.y);
            float yy2 = fminf(bj.z, my.z), xx2 = fminf(bj.w, my.w);
            float inter = fmaxf(yy2 - yy1, 0.f) * fmaxf(xx2 - xx1, 0.f);
            float iou = inter / (aj + myAr - inter + 1e-8f);   // exact ref expr (commutes)
            if (iou > IOU_THR) {
                if (kj > myKey) {                        // j earlier -> j suppresses me
                    u32 w = j >> 6; u64 bitj = 1ull << (j & 63);
                    if (w == 0) m0 |= bitj; else if (w == 1) m1 |= bitj; else m2 |= bitj;
                } else {                                  // I'm earlier -> I suppress j (rare)
                    atomicOr(&mask[j][myW], myBit);
                }
            }
        }
        if (m0) atomicOr(&mask[l][0], m0);
        if (m1) atomicOr(&mask[l][1], m1);
        if (m2) atomicOr(&mask[l][2], m2);
    }
    __syncthreads();

    // --- phase 3: wave 0 only — validated ballot fixpoint + append ---
    if (l >= 64) return;

    bool own[3]; u64 sKey[3];
    u64 msk0[3], msk1[3], msk2[3];
#pragma unroll
    for (int s = 0; s < 3; ++s) {
        u32 r = (u32)lane + 64u * (u32)s;
        own[s] = r < cnt;
        sKey[s] = own[s] ? kKey[r] : 0ull;
        msk0[s] = own[s] ? mask[r][0] : 0ull;
        msk1[s] = own[s] ? mask[r][1] : 0ull;
        msk2[s] = own[s] ? mask[r][2] : 0ull;
    }

    u64 KNOWN[3], ALIVE[3] = {0ull, 0ull, 0ull};
#pragma unroll
    for (int w = 0; w < 3; ++w) {
        int rem = (int)cnt - 64 * w;
        KNOWN[w] = (rem <= 0) ? ~0ull : ((rem >= 64) ? 0ull : (~0ull << rem));
    }
    while ((KNOWN[0] & KNOWN[1] & KNOWN[2]) != ~0ull) {
        bool kn[3] = {false, false, false}, al[3] = {false, false, false};
#pragma unroll
        for (int s = 0; s < 3; ++s) {
            if (own[s] && !((KNOWN[s] >> lane) & 1ull)) {
                u64 supAlive = (msk0[s] & ALIVE[0]) | (msk1[s] & ALIVE[1]) | (msk2[s] & ALIVE[2]);
                if (supAlive != 0ull) kn[s] = true;                       // dead
                else {
                    u64 supUnk = (msk0[s] & ~KNOWN[0]) | (msk1[s] & ~KNOWN[1]) | (msk2[s] & ~KNOWN[2]);
                    if (supUnk == 0ull) { kn[s] = true; al[s] = true; }   // alive
                }
            }
        }
#pragma unroll
        for (int s = 0; s < 3; ++s) {
            KNOWN[s] |= __ballot(kn[s]);
            ALIVE[s] |= __ballot(al[s]);
        }
    }

    u32 total = (u32)(__popcll(ALIVE[0]) + __popcll(ALIVE[1]) + __popcll(ALIVE[2]));
    if (total == 0) return;
    u32 abase = 0;
    if (lane == 0) abase = atomicAdd(survCount + b, total);
    abase = __shfl(abase, 0);
    const u32 pre0 = (u32)__popcll(ALIVE[0]);
    const u32 pre1 = pre0 + (u32)__popcll(ALIVE[1]);
    const u64 ltm = (1ull << lane) - 1ull;
#pragma unroll
    for (int s = 0; s < 3; ++s) {
        if ((ALIVE[s] >> lane) & 1ull) {
            u32 off = (s == 0 ? 0u : (s == 1 ? pre0 : pre1)) + (u32)__popcll(ALIVE[s] & ltm);
            u32 d = abase + off;
            if (d < SCAP) survKeys[(long long)b * SCAP + d] = sKey[s];
        }
    }
}

// ---------- kernel 3: per-image top-100, all phases parallel (validated r3/r4) ----------
__global__ __launch_bounds__(1024) void select_kernel(const float* __restrict__ rois,
                                                      const float* __restrict__ cls,
                                                      const float* __restrict__ window,
                                                      const u64* __restrict__ survKeys,
                                                      const u32* __restrict__ survCount,
                                                      float* __restrict__ out) {
#pragma clang fp contract(off)
    const int b = blockIdx.x;
    const int tid = threadIdx.x;
    const int lane = tid & 63, wid = tid >> 6;
    const u32 S = min(survCount[b], (u32)SCAP);
    __shared__ u32 hist[NB];
    __shared__ u32 wsum[16];
    __shared__ int sT;
    __shared__ u32 collCnt;
    __shared__ u64 coll[1024];
    __shared__ u64 order[MAX_DET];

    if (tid < NB) hist[tid] = 0u;
    if (tid == 0) { sT = 0; collCnt = 0u; }
    __syncthreads();

    const u64* sk = survKeys + (long long)b * SCAP;
    for (u32 i = tid; i < S; i += 1024) {
        u32 bkt = (u32)(sk[i] >> 45) - BASE13;
        atomicAdd(&hist[bkt], 1u);
    }
    __syncthreads();

    u32 v = (tid < NB) ? hist[tid] : 0u;
    u32 ws = v;
#pragma unroll
    for (int off = 1; off < 64; off <<= 1) ws += __shfl_xor(ws, off);
    if (lane == 0) wsum[wid] = ws;
    __syncthreads();

    bool cond = false;
    if (tid < NB) {
        u32 suffix = 0;
        for (int w = wid + 1; w < 16; ++w) suffix += wsum[w];
        const int end = (wid + 1) * 64;
        for (int i = tid; i < end; ++i) suffix += hist[i];
        cond = suffix >= MAX_DET;
    }
    u64 bal = __ballot(cond);
    if (lane == 0 && bal != 0ull) {
        int hb = 63 - __clzll((long long)bal);
        atomicMax(&sT, wid * 64 + hb);
    }
    __syncthreads();

    const int T = sT;
    for (u32 i = tid; i < S; i += 1024) {
        u64 k = sk[i];
        int bkt = (int)((u32)(k >> 45) - BASE13);
        if (bkt >= T) {
            u32 d = atomicAdd(&collCnt, 1u);
            if (d < 1024u) coll[d] = k;
        }
    }
    if (tid < MAX_DET) order[tid] = 0ull;
    __syncthreads();

    const u32 C = min(collCnt, 1024u);
    for (u32 t = tid; t < C; t += 1024) {
        u64 k = coll[t];
        u32 r = 0;
        for (u32 i = 0; i < C; ++i) r += (u32)(coll[i] > k);
        if (r < MAX_DET) order[r] = k;
    }
    __syncthreads();

    if (tid < MAX_DET) {
        u64 m = order[tid];
        float* row = out + ((long long)b * MAX_DET + tid) * 6;
        if (m != 0ull) {
            int n = 0x7FFF - (int)((m >> 7) & 0x7FFF);
            int cid = (int)(m & 0x7F);
            float score = __uint_as_float((u32)(m >> 32));
            float y1, x1, y2, x2;
            decode_box(rois, cls, (long long)b * NN + n,
                       window[b * 4 + 0], window[b * 4 + 1], window[b * 4 + 2], window[b * 4 + 3],
                       y1, x1, y2, x2);
            row[0] = y1; row[1] = x1; row[2] = y2; row[3] = x2;
            row[4] = (float)cid; row[5] = score;
        } else {
            row[0] = 0.f; row[1] = 0.f; row[2] = 0.f;
            row[3] = 0.f; row[4] = 0.f; row[5] = 0.f;
        }
    }
}

extern "C" void kernel_launch(void* const* d_in, const int* in_sizes, int n_in,
                              void* d_out, int out_size, void* d_ws, size_t ws_size,
                              hipStream_t stream) {
    const float* rois   = (const float*)d_in[0];
    const float* cls    = (const float*)d_in[1];
    const float* window = (const float*)d_in[2];
    float* out = (float*)d_out;

    u32* bucketCount = (u32*)d_ws;
    u32* survCount   = (u32*)((char*)d_ws + 12288);
    u64* bucketKeys  = (u64*)((char*)d_ws + 16384);
    const size_t bkBytes  = (size_t)BB * NC * BCAP * 8;    // 3,981,312
    const size_t boxBytes = (size_t)BB * NC * BCAP * 16;   // 7,962,624
    const size_t preNeed  = 16384 + bkBytes + boxBytes + (size_t)BB * SCAP * 8;

    hipMemsetAsync(d_ws, 0, 16384, stream);
    const int blocksPerImg = (NN + 255) / 256;

    if (ws_size >= preNeed) {
        float4* bucketBox = (float4*)((char*)d_ws + 16384 + bkBytes);
        u64* survKeys     = (u64*)((char*)d_ws + 16384 + bkBytes + boxBytes);
        filter_kernel<true><<<BB * blocksPerImg, 256, 0, stream>>>(
            rois, cls, window, bucketKeys, bucketBox, bucketCount);
        classnms_kernel<true><<<NPAIR, BCAP, 0, stream>>>(
            rois, cls, window, bucketKeys, bucketBox, bucketCount, survKeys, survCount);
        select_kernel<<<BB, 1024, 0, stream>>>(rois, cls, window, survKeys, survCount, out);
    } else {
        // fallback: on-demand decode (deterministic: ws_size fixed per session)
        u64* survKeys = (u64*)((char*)d_ws + 16384 + bkBytes);
        filter_kernel<false><<<BB * blocksPerImg, 256, 0, stream>>>(
            rois, cls, window, bucketKeys, nullptr, bucketCount);
        classnms_kernel<false><<<NPAIR, BCAP, 0, stream>>>(
            rois, cls, window, bucketKeys, nullptr, bucketCount, survKeys, survCount);
        select_kernel<<<BB, 1024, 0, stream>>>(rois, cls, window, survKeys, survCount, out);
    }
}

// Round 6
// 66.694 us; speedup vs baseline: 1.9304x; 1.5976x over previous
//
#include <hip/hip_runtime.h>
#include <stdint.h>

typedef unsigned long long u64;
typedef unsigned int u32;

#define BB 32
#define NN 30000
#define NC 81
#define MAX_DET 100
#define MIN_CONF 0.7f
#define IOU_THR 0.3f
#define BCAP 192               // per-(image,class) cap; mean 111, sd 10.5 (7.7 sigma); validated r1-r5
#define SCAP 10240             // per-image survivor cap; ~8900 expected
#define NB 640                 // score buckets for [0.7,1.0): 615 used
#define BASE13 (0x3F333333u >> 13)
#define NPAIR (BB * (NC - 1))  // 2560
#define CSTR 16                // counter stride in u32 (64B line padding)
#define FBLK 1024
#define FCHUNK ((NN + FBLK - 1) / FBLK)   // 30

// ws layout (PRE path):
//   0         : bucketCount u32[BB*NC*CSTR]     (165,888 B, one counter per 64B line)
//   165,888   : survCount   u32[BB*CSTR]        (2,048 B)
//   167,936   : bucketKeys  u64[BB*NC*BCAP]     (3,981,312 B)
//   4,149,248 : bucketBox   float4[BB*NC*BCAP]  (7,962,624 B)
//   12,111,872: survKeys    u64[BB*SCAP]        (2,621,440 B)   total 14,733,312 B

// ---------- decode (bit-exact vs reference; validated absmax 0 in r1-r5) ----------
__device__ __forceinline__ void decode_box(const float* __restrict__ rois,
                                           const float* __restrict__ cls,
                                           long long bn,
                                           float wy1, float wx1, float wy2, float wx2,
                                           float& y1, float& x1, float& y2, float& x2) {
#pragma clang fp contract(off)
    const float4 r   = *reinterpret_cast<const float4*>(rois + bn * 4);
    const float2 d01 = *reinterpret_cast<const float2*>(cls + bn * 6);
    const float2 d23 = *reinterpret_cast<const float2*>(cls + bn * 6 + 2);
    float dy = d01.x * 0.1f, dx = d01.y * 0.1f;
    float dh = d23.x * 0.2f, dw = d23.y * 0.2f;
    float h = r.z - r.x, w = r.w - r.y;
    float cy = r.x + 0.5f * h + dy * h;
    float cx = r.y + 0.5f * w + dx * w;
    h = h * expf(dh);
    w = w * expf(dw);
    y1 = cy - 0.5f * h; x1 = cx - 0.5f * w;
    y2 = cy + 0.5f * h; x2 = cx + 0.5f * w;
    y1 = fminf(fmaxf(y1, wy1), wy2);
    y2 = fminf(fmaxf(y2, wy1), wy2);
    x1 = fminf(fmaxf(x1, wx1), wx2);
    x2 = fminf(fmaxf(x2, wx1), wx2);
}

// ---------- kernel 1: filter + decode; LDS-aggregated bucket append ----------
// 1024 threads per block; per-cid counts aggregated in LDS -> <=81 padded global
// atomics per block; same-cid candidates land in consecutive slots (L2-coalesced).
template <bool PRE>
__global__ __launch_bounds__(FBLK) void filter_kernel(const float* __restrict__ rois,
                                                      const float* __restrict__ cls,
                                                      const float* __restrict__ window,
                                                      u64* __restrict__ bucketKeys,
                                                      float4* __restrict__ bucketBox,
                                                      u32* __restrict__ bucketCount) {
    const int b = blockIdx.x / FCHUNK;
    const int n = (blockIdx.x % FCHUNK) * FBLK + threadIdx.x;
    const int tid = threadIdx.x;

    __shared__ u32 lcnt[NC];
    __shared__ u32 gbase[NC];
    if (tid < NC) lcnt[tid] = 0u;
    __syncthreads();

    bool valid = false; int cid = 0; float score = 0.f;
    long long bn = 0;
    if (n < NN) {
        bn = (long long)b * NN + n;
        const float2 cs = *reinterpret_cast<const float2*>(cls + bn * 6 + 4);
        cid = (int)cs.x;
        score = cs.y;
        valid = (cid > 0) && (score >= MIN_CONF);
    }
    u32 lrank = 0;
    if (valid) lrank = atomicAdd(&lcnt[cid], 1u);
    __syncthreads();

    if (tid < NC) {
        u32 c = lcnt[tid];
        gbase[tid] = c ? atomicAdd(&bucketCount[(b * NC + tid) * CSTR], c) : 0u;
    }
    __syncthreads();

    if (valid) {
        u32 slot = gbase[cid] + lrank;
        if (slot < BCAP) {
            const long long dst = ((long long)(b * NC + cid)) * BCAP + slot;
            bucketKeys[dst] = ((u64)__float_as_uint(score) << 32)
                            | ((u64)(0x7FFF - n) << 7) | (u64)cid;
            if (PRE) {
                float y1, x1, y2, x2;
                decode_box(rois, cls, bn,
                           window[b * 4 + 0], window[b * 4 + 1],
                           window[b * 4 + 2], window[b * 4 + 3],
                           y1, x1, y2, x2);
                bucketBox[dst] = make_float4(y1, x1, y2, x2);
            }
        }
    }
}

// ---------- kernel 2: one block (192 thr) per (image,class); validated r5 ----------
template <bool PRE>
__global__ __launch_bounds__(BCAP) void classnms_kernel(
        const float* __restrict__ rois,
        const float* __restrict__ cls,
        const float* __restrict__ window,
        const u64* __restrict__ bucketKeys,
        const float4* __restrict__ bucketBox,
        const u32* __restrict__ bucketCount,
        u64* __restrict__ survKeys,
        u32* __restrict__ survCount) {
#pragma clang fp contract(off)
    const int pair = blockIdx.x;
    const int b = pair / (NC - 1);
    const int cid = 1 + pair % (NC - 1);
    const u32 cnt = min(bucketCount[(b * NC + cid) * CSTR], (u32)BCAP);
    if (cnt == 0) return;               // block-uniform exit (before any barrier)

    const int l = threadIdx.x;
    const int lane = l & 63;

    __shared__ u64 kKey[BCAP];
    __shared__ float4 kBox[BCAP];
    __shared__ float kArea[BCAP];
    __shared__ u64 mask[BCAP][3];

    const long long base = ((long long)(b * NC + cid)) * BCAP;

    mask[l][0] = 0ull; mask[l][1] = 0ull; mask[l][2] = 0ull;
    u64 myKey = 0ull; float4 my = make_float4(0.f, 0.f, 0.f, 0.f); float myAr = 0.f;
    const bool act = (u32)l < cnt;
    if (act) {
        myKey = bucketKeys[base + l];
        if (PRE) {
            my = bucketBox[base + l];
        } else {
            int n = 0x7FFF - (int)((myKey >> 7) & 0x7FFF);
            float y1, x1, y2, x2;
            decode_box(rois, cls, (long long)b * NN + n,
                       window[b * 4 + 0], window[b * 4 + 1],
                       window[b * 4 + 2], window[b * 4 + 3],
                       y1, x1, y2, x2);
            my = make_float4(y1, x1, y2, x2);
        }
        myAr = (my.z - my.x) * (my.w - my.y);
        kKey[l] = myKey; kBox[l] = my; kArea[l] = myAr;
    }
    __syncthreads();

    if (act) {
        u64 m0 = 0ull, m1 = 0ull, m2 = 0ull;
        const u32 myW = (u32)l >> 6;
        const u64 myBit = 1ull << (l & 63);
        const u32 T = cnt >> 1;
        for (u32 t = 1; t <= T; ++t) {
            u32 j = (u32)l + t; if (j >= cnt) j -= cnt;
            u64 kj = kKey[j];
            float4 bj = kBox[j];
            float aj = kArea[j];
            float yy1 = fmaxf(bj.x, my.x), xx1 = fmaxf(bj.y, my.y);
            float yy2 = fminf(bj.z, my.z), xx2 = fminf(bj.w, my.w);
            float inter = fmaxf(yy2 - yy1, 0.f) * fmaxf(xx2 - xx1, 0.f);
            float iou = inter / (aj + myAr - inter + 1e-8f);   // exact ref expr (commutes)
            if (iou > IOU_THR) {
                if (kj > myKey) {
                    u32 w = j >> 6; u64 bitj = 1ull << (j & 63);
                    if (w == 0) m0 |= bitj; else if (w == 1) m1 |= bitj; else m2 |= bitj;
                } else {
                    atomicOr(&mask[j][myW], myBit);
                }
            }
        }
        if (m0) atomicOr(&mask[l][0], m0);
        if (m1) atomicOr(&mask[l][1], m1);
        if (m2) atomicOr(&mask[l][2], m2);
    }
    __syncthreads();

    if (l >= 64) return;

    bool own[3]; u64 sKey[3];
    u64 msk0[3], msk1[3], msk2[3];
#pragma unroll
    for (int s = 0; s < 3; ++s) {
        u32 r = (u32)lane + 64u * (u32)s;
        own[s] = r < cnt;
        sKey[s] = own[s] ? kKey[r] : 0ull;
        msk0[s] = own[s] ? mask[r][0] : 0ull;
        msk1[s] = own[s] ? mask[r][1] : 0ull;
        msk2[s] = own[s] ? mask[r][2] : 0ull;
    }

    u64 KNOWN[3], ALIVE[3] = {0ull, 0ull, 0ull};
#pragma unroll
    for (int w = 0; w < 3; ++w) {
        int rem = (int)cnt - 64 * w;
        KNOWN[w] = (rem <= 0) ? ~0ull : ((rem >= 64) ? 0ull : (~0ull << rem));
    }
    while ((KNOWN[0] & KNOWN[1] & KNOWN[2]) != ~0ull) {
        bool kn[3] = {false, false, false}, al[3] = {false, false, false};
#pragma unroll
        for (int s = 0; s < 3; ++s) {
            if (own[s] && !((KNOWN[s] >> lane) & 1ull)) {
                u64 supAlive = (msk0[s] & ALIVE[0]) | (msk1[s] & ALIVE[1]) | (msk2[s] & ALIVE[2]);
                if (supAlive != 0ull) kn[s] = true;
                else {
                    u64 supUnk = (msk0[s] & ~KNOWN[0]) | (msk1[s] & ~KNOWN[1]) | (msk2[s] & ~KNOWN[2]);
                    if (supUnk == 0ull) { kn[s] = true; al[s] = true; }
                }
            }
        }
#pragma unroll
        for (int s = 0; s < 3; ++s) {
            KNOWN[s] |= __ballot(kn[s]);
            ALIVE[s] |= __ballot(al[s]);
        }
    }

    u32 total = (u32)(__popcll(ALIVE[0]) + __popcll(ALIVE[1]) + __popcll(ALIVE[2]));
    if (total == 0) return;
    u32 abase = 0;
    if (lane == 0) abase = atomicAdd(&survCount[b * CSTR], total);
    abase = __shfl(abase, 0);
    const u32 pre0 = (u32)__popcll(ALIVE[0]);
    const u32 pre1 = pre0 + (u32)__popcll(ALIVE[1]);
    const u64 ltm = (1ull << lane) - 1ull;
#pragma unroll
    for (int s = 0; s < 3; ++s) {
        if ((ALIVE[s] >> lane) & 1ull) {
            u32 off = (s == 0 ? 0u : (s == 1 ? pre0 : pre1)) + (u32)__popcll(ALIVE[s] & ltm);
            u32 d = abase + off;
            if (d < SCAP) survKeys[(long long)b * SCAP + d] = sKey[s];
        }
    }
}

// ---------- kernel 3: per-image top-100, all phases parallel (validated r3-r5) ----------
__global__ __launch_bounds__(1024) void select_kernel(const float* __restrict__ rois,
                                                      const float* __restrict__ cls,
                                                      const float* __restrict__ window,
                                                      const u64* __restrict__ survKeys,
                                                      const u32* __restrict__ survCount,
                                                      float* __restrict__ out) {
#pragma clang fp contract(off)
    const int b = blockIdx.x;
    const int tid = threadIdx.x;
    const int lane = tid & 63, wid = tid >> 6;
    const u32 S = min(survCount[b * CSTR], (u32)SCAP);
    __shared__ u32 hist[NB];
    __shared__ u32 wsum[16];
    __shared__ int sT;
    __shared__ u32 collCnt;
    __shared__ u64 coll[1024];
    __shared__ u64 order[MAX_DET];

    if (tid < NB) hist[tid] = 0u;
    if (tid == 0) { sT = 0; collCnt = 0u; }
    __syncthreads();

    const u64* sk = survKeys + (long long)b * SCAP;
    for (u32 i = tid; i < S; i += 1024) {
        u32 bkt = (u32)(sk[i] >> 45) - BASE13;
        atomicAdd(&hist[bkt], 1u);
    }
    __syncthreads();

    u32 v = (tid < NB) ? hist[tid] : 0u;
    u32 ws = v;
#pragma unroll
    for (int off = 1; off < 64; off <<= 1) ws += __shfl_xor(ws, off);
    if (lane == 0) wsum[wid] = ws;
    __syncthreads();

    bool cond = false;
    if (tid < NB) {
        u32 suffix = 0;
        for (int w = wid + 1; w < 16; ++w) suffix += wsum[w];
        const int end = (wid + 1) * 64;
        for (int i = tid; i < end; ++i) suffix += hist[i];
        cond = suffix >= MAX_DET;
    }
    u64 bal = __ballot(cond);
    if (lane == 0 && bal != 0ull) {
        int hb = 63 - __clzll((long long)bal);
        atomicMax(&sT, wid * 64 + hb);
    }
    __syncthreads();

    const int T = sT;
    for (u32 i = tid; i < S; i += 1024) {
        u64 k = sk[i];
        int bkt = (int)((u32)(k >> 45) - BASE13);
        if (bkt >= T) {
            u32 d = atomicAdd(&collCnt, 1u);
            if (d < 1024u) coll[d] = k;
        }
    }
    if (tid < MAX_DET) order[tid] = 0ull;
    __syncthreads();

    const u32 C = min(collCnt, 1024u);
    for (u32 t = tid; t < C; t += 1024) {
        u64 k = coll[t];
        u32 r = 0;
        for (u32 i = 0; i < C; ++i) r += (u32)(coll[i] > k);
        if (r < MAX_DET) order[r] = k;
    }
    __syncthreads();

    if (tid < MAX_DET) {
        u64 m = order[tid];
        float* row = out + ((long long)b * MAX_DET + tid) * 6;
        if (m != 0ull) {
            int n = 0x7FFF - (int)((m >> 7) & 0x7FFF);
            int cid = (int)(m & 0x7F);
            float score = __uint_as_float((u32)(m >> 32));
            float y1, x1, y2, x2;
            decode_box(rois, cls, (long long)b * NN + n,
                       window[b * 4 + 0], window[b * 4 + 1], window[b * 4 + 2], window[b * 4 + 3],
                       y1, x1, y2, x2);
            row[0] = y1; row[1] = x1; row[2] = y2; row[3] = x2;
            row[4] = (float)cid; row[5] = score;
        } else {
            row[0] = 0.f; row[1] = 0.f; row[2] = 0.f;
            row[3] = 0.f; row[4] = 0.f; row[5] = 0.f;
        }
    }
}

extern "C" void kernel_launch(void* const* d_in, const int* in_sizes, int n_in,
                              void* d_out, int out_size, void* d_ws, size_t ws_size,
                              hipStream_t stream) {
    const float* rois   = (const float*)d_in[0];
    const float* cls    = (const float*)d_in[1];
    const float* window = (const float*)d_in[2];
    float* out = (float*)d_out;

    const size_t cntBytes = (size_t)BB * NC * CSTR * 4;    // 165,888
    const size_t svcBytes = (size_t)BB * CSTR * 4;         // 2,048
    const size_t hdrBytes = cntBytes + svcBytes;           // 167,936
    const size_t bkBytes  = (size_t)BB * NC * BCAP * 8;    // 3,981,312
    const size_t boxBytes = (size_t)BB * NC * BCAP * 16;   // 7,962,624
    const size_t preNeed  = hdrBytes + bkBytes + boxBytes + (size_t)BB * SCAP * 8;

    u32* bucketCount = (u32*)d_ws;
    u32* survCount   = (u32*)((char*)d_ws + cntBytes);
    u64* bucketKeys  = (u64*)((char*)d_ws + hdrBytes);

    hipMemsetAsync(d_ws, 0, hdrBytes, stream);

    if (ws_size >= preNeed) {
        float4* bucketBox = (float4*)((char*)d_ws + hdrBytes + bkBytes);
        u64* survKeys     = (u64*)((char*)d_ws + hdrBytes + bkBytes + boxBytes);
        filter_kernel<true><<<BB * FCHUNK, FBLK, 0, stream>>>(
            rois, cls, window, bucketKeys, bucketBox, bucketCount);
        classnms_kernel<true><<<NPAIR, BCAP, 0, stream>>>(
            rois, cls, window, bucketKeys, bucketBox, bucketCount, survKeys, survCount);
        select_kernel<<<BB, 1024, 0, stream>>>(rois, cls, window, survKeys, survCount, out);
    } else {
        // fallback: on-demand decode (deterministic: ws_size fixed per session)
        u64* survKeys = (u64*)((char*)d_ws + hdrBytes + bkBytes);
        filter_kernel<false><<<BB * FCHUNK, FBLK, 0, stream>>>(
            rois, cls, window, bucketKeys, nullptr, bucketCount);
        classnms_kernel<false><<<NPAIR, BCAP, 0, stream>>>(
            rois, cls, window, bucketKeys, nullptr, bucketCount, survKeys, survCount);
        select_kernel<<<BB, 1024, 0, stream>>>(rois, cls, window, survKeys, survCount, out);
    }
}